// Round 3
// baseline (830.403 us; speedup 1.0000x reference)
//
#include <hip/hip_runtime.h>

#define NROWS 8192
#define FIN 1024
#define FOUT 512

typedef __attribute__((ext_vector_type(8))) short short8;
typedef __attribute__((ext_vector_type(4))) float f32x4;
typedef __attribute__((ext_vector_type(4))) unsigned short us4;

static __device__ __forceinline__ unsigned short f2bf(float f) {
  unsigned int u = __float_as_uint(f);
  u += 0x7fffu + ((u >> 16) & 1u);
  return (unsigned short)(u >> 16);
}
static __device__ __forceinline__ float bf2f(unsigned short h) {
  return __uint_as_float(((unsigned int)h) << 16);
}
static __device__ __forceinline__ void load_lds16(const void* g, void* l) {
  __builtin_amdgcn_global_load_lds((const __attribute__((address_space(1))) void*)g,
                                   (__attribute__((address_space(3))) void*)l, 16, 0, 0);
}

// ---------------- split-cast: fp32 -> (bf16 hi, bf16 lo residual) -------------
__global__ void k_split(const float* __restrict__ x, const float* __restrict__ w,
                        unsigned short* __restrict__ hi, unsigned short* __restrict__ lo) {
  long long base = ((long long)blockIdx.x * blockDim.x + threadIdx.x) * 4;
  const long long NX = (long long)NROWS * FIN;
  const float* src = (base < NX) ? (x + base) : (w + (base - NX));
  float4 v = *(const float4*)src;
  unsigned short h0 = f2bf(v.x), h1 = f2bf(v.y), h2 = f2bf(v.z), h3 = f2bf(v.w);
  us4 hv = {h0, h1, h2, h3};
  us4 lv = {f2bf(v.x - bf2f(h0)), f2bf(v.y - bf2f(h1)),
            f2bf(v.z - bf2f(h2)), f2bf(v.w - bf2f(h3))};
  *(us4*)(hi + base) = hv;
  *(us4*)(lo + base) = lv;
}

// ---------------- GEMM1 + fused epilogue ------------------------------------
// seq_fts tile (128x64) in regs -> LDS -> (a) f1/f2 partial dots via atomicAdd,
// (b) vtp B-fragment pack. sf never goes to global.
__global__ __launch_bounds__(256) void k_gemm1(const unsigned short* __restrict__ ah,
                                               const unsigned short* __restrict__ al,
                                               const float* __restrict__ f1w,
                                               const float* __restrict__ f2w,
                                               float* __restrict__ f1,
                                               float* __restrict__ f2,
                                               unsigned short* __restrict__ vtp) {
  __shared__ unsigned short sAh[128 * 32], sAl[128 * 32], sBh[64 * 32], sBl[64 * 32];
  __shared__ float sC[128][65];
  const int tid = threadIdx.x;
  const int w = tid >> 6, l = tid & 63;
  const int bm = blockIdx.x >> 3, bn = blockIdx.x & 7;
  const int i0 = bm * 128, n0 = bn * 64;
  const unsigned short* bhp = ah + (long long)NROWS * FIN;
  const unsigned short* blp = al + (long long)NROWS * FIN;
  const int m_off = (w & 1) * 64, n_off = (w >> 1) * 32;
  const int lrow = l >> 2, lch = (l & 3) * 8;
  f32x4 acc[4][2] = {};
  for (int k0 = 0; k0 < FIN; k0 += 32) {
    __syncthreads();
    {
      int rA0 = w * 32, rA1 = w * 32 + 16, rB = w * 16;
      long long ga0 = (long long)(i0 + rA0 + lrow) * FIN + k0 + lch;
      long long ga1 = (long long)(i0 + rA1 + lrow) * FIN + k0 + lch;
      long long gb = (long long)(n0 + rB + lrow) * FIN + k0 + lch;
      load_lds16(ah + ga0, &sAh[rA0 * 32]);
      load_lds16(ah + ga1, &sAh[rA1 * 32]);
      load_lds16(al + ga0, &sAl[rA0 * 32]);
      load_lds16(al + ga1, &sAl[rA1 * 32]);
      load_lds16(bhp + gb, &sBh[rB * 32]);
      load_lds16(blp + gb, &sBl[rB * 32]);
    }
    __syncthreads();
    short8 a_h[4], a_l[4], b_h[2], b_l[2];
#pragma unroll
    for (int mi = 0; mi < 4; ++mi) {
      int off = (m_off + mi * 16 + (l & 15)) * 32 + (l >> 4) * 8;
      a_h[mi] = *(const short8*)&sAh[off];
      a_l[mi] = *(const short8*)&sAl[off];
    }
#pragma unroll
    for (int ni = 0; ni < 2; ++ni) {
      int off = (n_off + ni * 16 + (l & 15)) * 32 + (l >> 4) * 8;
      b_h[ni] = *(const short8*)&sBh[off];
      b_l[ni] = *(const short8*)&sBl[off];
    }
#pragma unroll
    for (int mi = 0; mi < 4; ++mi)
#pragma unroll
      for (int ni = 0; ni < 2; ++ni) {
        acc[mi][ni] = __builtin_amdgcn_mfma_f32_16x16x32_bf16(a_h[mi], b_h[ni], acc[mi][ni], 0, 0, 0);
        acc[mi][ni] = __builtin_amdgcn_mfma_f32_16x16x32_bf16(a_h[mi], b_l[ni], acc[mi][ni], 0, 0, 0);
        acc[mi][ni] = __builtin_amdgcn_mfma_f32_16x16x32_bf16(a_l[mi], b_h[ni], acc[mi][ni], 0, 0, 0);
      }
  }
  // ---- epilogue: regs -> LDS ----
#pragma unroll
  for (int mi = 0; mi < 4; ++mi)
#pragma unroll
    for (int ni = 0; ni < 2; ++ni)
#pragma unroll
      for (int rg = 0; rg < 4; ++rg)
        sC[m_off + mi * 16 + (l >> 4) * 4 + rg][n_off + ni * 16 + (l & 15)] = acc[mi][ni][rg];
  __syncthreads();
  // f1/f2 partial dots: thread = (half, row)
  {
    int row = tid & 127, half = tid >> 7;
    float s1 = 0.f, s2 = 0.f;
#pragma unroll 8
    for (int c = 0; c < 32; ++c) {
      float v = sC[row][half * 32 + c];
      s1 += v * f1w[n0 + half * 32 + c];
      s2 += v * f2w[n0 + half * 32 + c];
    }
    atomicAdd(&f1[i0 + row], s1);
    atomicAdd(&f2[i0 + row], s2);
  }
  // vtp pack: fragment (kt,nt,lane) holds V[kt*32+(lane>>4)*8+j][nt*16+(lane&15)]
  {
    int lam = tid & 63, ktl = tid >> 6;
#pragma unroll
    for (int ntl = 0; ntl < 4; ++ntl) {
      short8 pv;
#pragma unroll
      for (int j = 0; j < 8; ++j)
        pv[j] = (short)f2bf(sC[ktl * 32 + (lam >> 4) * 8 + j][ntl * 16 + (lam & 15)]);
      long long kt_g = (i0 >> 5) + ktl;
      long long nt_g = (n0 >> 4) + ntl;
      *(short8*)(vtp + ((kt_g * 32 + nt_g) * 64 + lam) * 8) = pv;
    }
  }
}

// ---------------- flash attention: wave-autonomous, no loop barriers ---------
// Wave owns 16 Q-rows x 128 out-cols. Lane l: row=l&15, j-chunk=(l>>4)*8
// (exactly the MFMA A-fragment layout -> P stays in registers).
__global__ __launch_bounds__(256, 3) void k_flash(const float* __restrict__ adj,
                                                  const float* __restrict__ f1,
                                                  const float* __restrict__ f2,
                                                  const unsigned short* __restrict__ vtp,
                                                  const float* __restrict__ bias,
                                                  const float* __restrict__ f1b,
                                                  const float* __restrict__ f2b,
                                                  float* __restrict__ out) {
  __shared__ float ls[4][16];
  const int tid = threadIdx.x, l = tid & 63, w = tid >> 6;
  // XCD swizzle: XCD pair {2y,2y+1} covers col-slice y -> 2MB V slice L2-resident
  const int id = blockIdx.x;
  const int xcd = id & 7, seq = id >> 3;
  const int by = xcd >> 1;
  const int bx = seq + ((xcd & 1) << 6);
  const int r0 = bx * 64 + w * 16;
  const int nt0 = by * 8;
  const int row = r0 + (l & 15);
  const int jq = (l >> 4) * 8;
  const long long arow = (long long)row * NROWS;
  const float fr = f1[row] + f1b[0] + f2b[0];
  float m = -3.0e38f, lsum = 0.f;
  f32x4 acc[8] = {};
  // depth-2 pipeline buffers
  float4 A0a = *(const float4*)(adj + arow + jq);
  float4 A1a = *(const float4*)(adj + arow + jq + 4);
  float4 F0a = *(const float4*)(f2 + jq);
  float4 F1a = *(const float4*)(f2 + jq + 4);
  float4 A0b = *(const float4*)(adj + arow + 32 + jq);
  float4 A1b = *(const float4*)(adj + arow + 32 + jq + 4);
  float4 F0b = *(const float4*)(f2 + 32 + jq);
  float4 F1b = *(const float4*)(f2 + 32 + jq + 4);

  auto step = [&](int j0, int jn, float4& A0, float4& A1, float4& F0, float4& F1) {
    // B fragments (L1/L2-hot): issue early, consumed ~300 VALU cycles later
    const unsigned short* bb = vtp + (((long long)(j0 >> 5) * 32 + nt0) * 64 + l) * 8;
    short8 bfr[8];
#pragma unroll
    for (int ni = 0; ni < 8; ++ni) bfr[ni] = *(const short8*)(bb + ni * 512);
    float p[8];
    {
      float z;
      z = fr + F0.x; z = fmaxf(z, 0.2f * z); p[0] = z + A0.x;
      z = fr + F0.y; z = fmaxf(z, 0.2f * z); p[1] = z + A0.y;
      z = fr + F0.z; z = fmaxf(z, 0.2f * z); p[2] = z + A0.z;
      z = fr + F0.w; z = fmaxf(z, 0.2f * z); p[3] = z + A0.w;
      z = fr + F1.x; z = fmaxf(z, 0.2f * z); p[4] = z + A1.x;
      z = fr + F1.y; z = fmaxf(z, 0.2f * z); p[5] = z + A1.y;
      z = fr + F1.z; z = fmaxf(z, 0.2f * z); p[6] = z + A1.z;
      z = fr + F1.w; z = fmaxf(z, 0.2f * z); p[7] = z + A1.w;
    }
    // prefetch j = jn into the same buffers (consumed 2 iterations later)
    A0 = *(const float4*)(adj + arow + jn + jq);
    A1 = *(const float4*)(adj + arow + jn + jq + 4);
    F0 = *(const float4*)(f2 + jn + jq);
    F1 = *(const float4*)(f2 + jn + jq + 4);
    float mt = fmaxf(fmaxf(fmaxf(p[0], p[1]), fmaxf(p[2], p[3])),
                     fmaxf(fmaxf(p[4], p[5]), fmaxf(p[6], p[7])));
    mt = fmaxf(mt, __shfl_xor(mt, 16, 64));
    mt = fmaxf(mt, __shfl_xor(mt, 32, 64));
    float mn = fmaxf(m, mt);
    int upd = mn > m;
    float al = __expf(m - mn);
#pragma unroll
    for (int j = 0; j < 8; ++j) p[j] = __expf(p[j] - mn);
    float ps = ((p[0] + p[1]) + (p[2] + p[3])) + ((p[4] + p[5]) + (p[6] + p[7]));
    ps += __shfl_xor(ps, 16, 64);
    ps += __shfl_xor(ps, 32, 64);
    lsum = lsum * al + ps;
    m = mn;
    short8 pv;
#pragma unroll
    for (int j = 0; j < 8; ++j) pv[j] = (short)f2bf(p[j]);
    if (__any(upd)) {  // rare after warm-up; wave-uniform branch
      float ar[4];
#pragma unroll
      for (int rg = 0; rg < 4; ++rg) ar[rg] = __shfl(al, (l >> 4) * 4 + rg, 64);
#pragma unroll
      for (int ni = 0; ni < 8; ++ni)
#pragma unroll
        for (int rg = 0; rg < 4; ++rg) acc[ni][rg] *= ar[rg];
    }
#pragma unroll
    for (int ni = 0; ni < 8; ++ni)
      acc[ni] = __builtin_amdgcn_mfma_f32_16x16x32_bf16(pv, bfr[ni], acc[ni], 0, 0, 0);
  };

  for (int t = 0; t < 256; t += 2) {
    int jnA = (t + 2 < 256) ? (t + 2) * 32 : 0;
    int jnB = (t + 3 < 256) ? (t + 3) * 32 : 0;
    step(t * 32, jnA, A0a, A1a, F0a, F1a);
    step((t + 1) * 32, jnB, A0b, A1b, F0b, F1b);
  }

  if (l < 16) ls[w][l] = lsum;
  __syncthreads();
#pragma unroll
  for (int rg = 0; rg < 4; ++rg) {
    int rr = (l >> 4) * 4 + rg;
    float linv = 1.0f / ls[w][rr];
    long long go = (long long)(r0 + rr) * FOUT;
#pragma unroll
    for (int ni = 0; ni < 8; ++ni) {
      int col = by * 128 + ni * 16 + (l & 15);
      float v = acc[ni][rg] * linv + bias[col];
      out[go + col] = v > 0.f ? v : (__expf(v) - 1.f);
    }
  }
}

// ---------------- rwr: ri from per-row count of adj_ad in {2,3} --------------
__global__ void k_rwr(const int* __restrict__ adj_ad, float* __restrict__ out) {
  __shared__ int ssum[4];
  const int tid = threadIdx.x, row = blockIdx.x;
  const long long base = (long long)row * NROWS;
  int cnt = 0;
#pragma unroll
  for (int k = 0; k < 8; ++k) {
    int4 v = *(const int4*)(adj_ad + base + ((long long)(k * 256 + tid)) * 4);
    cnt += (v.x > 1 && v.x < 4) + (v.y > 1 && v.y < 4) + (v.z > 1 && v.z < 4) + (v.w > 1 && v.w < 4);
  }
#pragma unroll
  for (int mws = 1; mws < 64; mws <<= 1) cnt += __shfl_xor(cnt, mws, 64);
  if ((tid & 63) == 0) ssum[tid >> 6] = cnt;
  __syncthreads();
  if (tid == 0) {
    float kk = (float)(ssum[0] + ssum[1] + ssum[2] + ssum[3]);
    float denom = 1.0f - 0.25f * kk;
    float r0, rn;
    if (denom == 0.0f) { r0 = 1.0f; rn = 0.5f; }
    else { r0 = fabsf(1.0f / denom); rn = fabsf(0.5f / denom); }
    out[(long long)NROWS * FOUT + row * 2] = r0;
    out[(long long)NROWS * FOUT + row * 2 + 1] = rn;
  }
}

extern "C" void kernel_launch(void* const* d_in, const int* in_sizes, int n_in,
                              void* d_out, int out_size, void* d_ws, size_t ws_size,
                              hipStream_t stream) {
  const float* x = (const float*)d_in[0];
  const float* adj = (const float*)d_in[1];
  const int* adj_ad = (const int*)d_in[2];
  const float* f1w = (const float*)d_in[4];
  const float* f1b = (const float*)d_in[5];
  const float* f2w = (const float*)d_in[6];
  const float* f2b = (const float*)d_in[7];
  const float* bias = (const float*)d_in[8];
  float* out = (float*)d_out;

  char* ws = (char*)d_ws;
  unsigned short* ah = (unsigned short*)ws;                  // (N+FOUT)*FIN bf16 hi
  unsigned short* al = (unsigned short*)(ws + 17825792LL);   // lo residual
  unsigned short* vtp = (unsigned short*)(ws + 35651584LL);  // packed V frags, 8 MB
  float* f1 = (float*)(ws + 44040192LL);
  float* f2 = (float*)(ws + 44072960LL);                     // total 44,105,728 B

  hipMemsetAsync(ws + 44040192LL, 0, 65536, stream);  // zero f1/f2 accumulators
  hipLaunchKernelGGL(k_split, dim3(8704), dim3(256), 0, stream, x, (const float*)d_in[3], ah, al);
  hipLaunchKernelGGL(k_gemm1, dim3(512), dim3(256), 0, stream, ah, al, f1w, f2w, f1, f2, vtp);
  hipLaunchKernelGGL(k_flash, dim3(512), dim3(256), 0, stream, adj, f1, f2, vtp, bias, f1b, f2b, out);
  hipLaunchKernelGGL(k_rwr, dim3(8192), dim3(256), 0, stream, adj_ad, out);
}